// Round 9
// baseline (353.569 us; speedup 1.0000x reference)
//
#include <hip/hip_runtime.h>
#include <hip/hip_bf16.h>

#define HDIM 128
#define BM 64
#define KB 16

// ---------------------------------------------------------------------------
// Tiled fp32 GEMM: out = A[n,128] @ W[128,128] (+bias), fp32 math.
// BF16OUT: epilogue converts to bf16 (messages consumed by the gather).
// ---------------------------------------------------------------------------
template <bool BF16OUT>
__global__ __launch_bounds__(256) void gemm_tiled(
    const float* __restrict__ A, const float* __restrict__ W,
    const float* __restrict__ bias, float* __restrict__ outf,
    __hip_bfloat16* __restrict__ outb, int n) {
  __shared__ float sA[KB][BM];    // transposed: sA[k][row]
  __shared__ float sW[KB][HDIM];
  const int tid = threadIdx.x;
  const int tx = tid & 15;        // col group: cols tx*8 .. tx*8+7
  const int ty = tid >> 4;        // row group: rows ty*4 .. ty*4+3
  const int block_row = blockIdx.x * BM;

  float acc[4][8];
#pragma unroll
  for (int i = 0; i < 4; ++i)
#pragma unroll
    for (int j = 0; j < 8; ++j) acc[i][j] = 0.f;

  const int ar = tid >> 2;        // 0..63: row this thread stages
  const int ak = (tid & 3) << 2;  // 0,4,8,12: k-offset staged
  const int wk = tid >> 4;        // 0..15: W k-row staged
  const int wc = (tid & 15) << 3; // col offset staged

  for (int k0 = 0; k0 < HDIM; k0 += KB) {
    float4 av = make_float4(0.f, 0.f, 0.f, 0.f);
    int grow = block_row + ar;
    if (grow < n) av = *(const float4*)(A + (size_t)grow * HDIM + k0 + ak);
    sA[ak + 0][ar] = av.x; sA[ak + 1][ar] = av.y;
    sA[ak + 2][ar] = av.z; sA[ak + 3][ar] = av.w;

    float4 w0 = *(const float4*)(W + (size_t)(k0 + wk) * HDIM + wc);
    float4 w1 = *(const float4*)(W + (size_t)(k0 + wk) * HDIM + wc + 4);
    *(float4*)&sW[wk][wc] = w0;
    *(float4*)&sW[wk][wc + 4] = w1;
    __syncthreads();

#pragma unroll
    for (int k = 0; k < KB; ++k) {
      float4 a = *(const float4*)&sA[k][ty * 4];
      float4 wA = *(const float4*)&sW[k][tx * 8];
      float4 wB = *(const float4*)&sW[k][tx * 8 + 4];
      float av4[4] = {a.x, a.y, a.z, a.w};
      float wv[8] = {wA.x, wA.y, wA.z, wA.w, wB.x, wB.y, wB.z, wB.w};
#pragma unroll
      for (int i = 0; i < 4; ++i)
#pragma unroll
        for (int j = 0; j < 8; ++j) acc[i][j] += av4[i] * wv[j];
    }
    __syncthreads();
  }

  float bj[8];
#pragma unroll
  for (int j = 0; j < 8; ++j) bj[j] = bias ? bias[tx * 8 + j] : 0.f;
#pragma unroll
  for (int i = 0; i < 4; ++i) {
    int grow = block_row + ty * 4 + i;
    if (grow < n) {
      float o[8];
#pragma unroll
      for (int j = 0; j < 8; ++j) o[j] = acc[i][j] + bj[j];
      if (BF16OUT) {
        uint32_t pk[4];
#pragma unroll
        for (int p = 0; p < 4; ++p) {
          uint32_t lo = __bfloat16_as_ushort(__float2bfloat16(o[2 * p]));
          uint32_t hi = __bfloat16_as_ushort(__float2bfloat16(o[2 * p + 1]));
          pk[p] = lo | (hi << 16);
        }
        *(uint4*)(outb + (size_t)grow * HDIM + tx * 8) = *(uint4*)pk;
      } else {
        *(float4*)(outf + (size_t)grow * HDIM + tx * 8) = *(float4*)&o[0];
        *(float4*)(outf + (size_t)grow * HDIM + tx * 8 + 4) = *(float4*)&o[4];
      }
    }
  }
}

// ---------------------------------------------------------------------------
// CSR build: histogram of dst, 3-kernel hierarchical exclusive scan, fill.
// ---------------------------------------------------------------------------
__global__ __launch_bounds__(256) void hist_dst(const int* __restrict__ ei,
                                                int E, int n,
                                                int* __restrict__ deg) {
  int e = blockIdx.x * 256 + threadIdx.x;
  if (e < E) {
    int s = ei[e];
    int d = ei[E + e];
    if ((unsigned)s < (unsigned)n && (unsigned)d < (unsigned)n)
      atomicAdd(&deg[d], 1);
  }
}

__global__ __launch_bounds__(1024) void scan1(const int* __restrict__ deg,
                                              int* __restrict__ partials, int n) {
  __shared__ int sm[1024];
  int i = blockIdx.x * 1024 + threadIdx.x;
  sm[threadIdx.x] = (i < n) ? deg[i] : 0;
  __syncthreads();
  for (int d = 512; d > 0; d >>= 1) {
    if (threadIdx.x < d) sm[threadIdx.x] += sm[threadIdx.x + d];
    __syncthreads();
  }
  if (threadIdx.x == 0) partials[blockIdx.x] = sm[0];
}

__global__ __launch_bounds__(1024) void scan2(int* __restrict__ partials, int G) {
  __shared__ int sm[1024];
  int tid = threadIdx.x;
  int v = (tid < G) ? partials[tid] : 0;
  sm[tid] = v;
  __syncthreads();
  for (int d = 1; d < 1024; d <<= 1) {
    int t = (tid >= d) ? sm[tid - d] : 0;
    __syncthreads();
    sm[tid] += t;
    __syncthreads();
  }
  if (tid < G) partials[tid] = sm[tid] - v;  // inclusive -> exclusive
}

__global__ __launch_bounds__(1024) void scan3(const int* __restrict__ deg,
                                              const int* __restrict__ partials,
                                              int* __restrict__ off,
                                              int* __restrict__ cur, int n) {
  __shared__ int sm[1024];
  int tid = threadIdx.x;
  int i = blockIdx.x * 1024 + tid;
  int v = (i < n) ? deg[i] : 0;
  sm[tid] = v;
  __syncthreads();
  for (int d = 1; d < 1024; d <<= 1) {
    int t = (tid >= d) ? sm[tid - d] : 0;
    __syncthreads();
    sm[tid] += t;
    __syncthreads();
  }
  if (i < n) {
    int ex = partials[blockIdx.x] + sm[tid] - v;
    off[i] = ex;
    cur[i] = ex;
    if (i == n - 1) off[n] = ex + v;
  }
}

__global__ __launch_bounds__(256) void fill_csr(const int* __restrict__ ei,
                                                int E, int n,
                                                int* __restrict__ cur,
                                                int* __restrict__ csr) {
  int e = blockIdx.x * 256 + threadIdx.x;
  if (e < E) {
    int s = ei[e];
    int d = ei[E + e];
    if ((unsigned)d < (unsigned)n && (unsigned)s < (unsigned)n) {
      int slot = atomicAdd(&cur[d], 1);
      csr[slot] = s;
    }
  }
}

// ---------------------------------------------------------------------------
// Gather core: fp32 accumulate of bf16 message rows.
// One wave per node; lane owns feats 2*lane, 2*lane+1 (one u32 per row).
// 8-deep batched loads for memory-level parallelism.
// ---------------------------------------------------------------------------
__device__ inline float2 bf2_unpack(uint32_t u) {
  float lo = __uint_as_float(u << 16);
  float hi = __uint_as_float(u & 0xffff0000u);
  return make_float2(lo, hi);
}

__device__ inline float2 gather_sum(const __hip_bfloat16* __restrict__ M,
                                    const int* __restrict__ off,
                                    const int* __restrict__ csr,
                                    int node, int lane) {
  const uint32_t* Mw = (const uint32_t*)M;  // row stride HDIM/2 u32
  // self loop
  float2 acc = bf2_unpack(Mw[(size_t)node * (HDIM / 2) + lane]);
  int s = off[node], e = off[node + 1];
  for (int base = s; base < e; base += 64) {
    int idx = base + lane;
    int msrc = (idx < e) ? csr[idx] : 0;
    int cnt = min(64, e - base);
    for (int j = 0; j < cnt; j += 8) {
      float2 v[8];
#pragma unroll
      for (int u = 0; u < 8; ++u) {
        v[u] = make_float2(0.f, 0.f);
        if (j + u < cnt) {  // wave-uniform predicate
          int src = __shfl(msrc, j + u);
          v[u] = bf2_unpack(Mw[(size_t)src * (HDIM / 2) + lane]);
        }
      }
#pragma unroll
      for (int u = 0; u < 8; ++u) {
        acc.x += v[u].x;
        acc.y += v[u].y;
      }
    }
  }
  return acc;
}

// agg_tanh: out[v] = tanh(bias + self + neighbor sum), fp32 out.
__global__ __launch_bounds__(256) void agg_tanh(
    const __hip_bfloat16* __restrict__ M, const int* __restrict__ off,
    const int* __restrict__ csr, const float* __restrict__ bias,
    float* __restrict__ out, int n) {
  int node = (blockIdx.x * 256 + threadIdx.x) >> 6;
  int lane = threadIdx.x & 63;
  if (node >= n) return;
  int f = lane * 2;
  float2 acc = gather_sum(M, off, csr, node, lane);
  acc.x = tanhf(acc.x + bias[f]);
  acc.y = tanhf(acc.y + bias[f + 1]);
  *(float2*)(out + (size_t)node * HDIM + f) = acc;
}

// agg2_head: layer-2 aggregation fused with class_prepare + classifier.
// d_out = [n*4 logits][n*2 hp].
__global__ __launch_bounds__(256) void agg2_head(
    const __hip_bfloat16* __restrict__ M, const int* __restrict__ off,
    const int* __restrict__ csr, const float* __restrict__ b2,
    const float* __restrict__ cp_w, const float* __restrict__ cp_b,
    const float* __restrict__ cls_w, const float* __restrict__ cls_b,
    float* __restrict__ out, int n) {
  int node = (blockIdx.x * 256 + threadIdx.x) >> 6;
  int lane = threadIdx.x & 63;
  if (node >= n) return;
  int f = lane * 2;
  float2 acc = gather_sum(M, off, csr, node, lane);
  float h0 = tanhf(acc.x + b2[f]);
  float h1 = tanhf(acc.y + b2[f + 1]);
  float4 w = *(const float4*)(cp_w + lane * 4);  // rows f, f+1 of [128,2]
  float s0 = h0 * w.x + h1 * w.z;
  float s1 = h0 * w.y + h1 * w.w;
#pragma unroll
  for (int offs = 32; offs; offs >>= 1) {
    s0 += __shfl_xor(s0, offs);
    s1 += __shfl_xor(s1, offs);
  }
  if (lane == 0) {
    float p0 = tanhf(s0 + cp_b[0]);
    float p1 = tanhf(s1 + cp_b[1]);
    float4 o;
    o.x = p0 * cls_w[0] + p1 * cls_w[4] + cls_b[0];
    o.y = p0 * cls_w[1] + p1 * cls_w[5] + cls_b[1];
    o.z = p0 * cls_w[2] + p1 * cls_w[6] + cls_b[2];
    o.w = p0 * cls_w[3] + p1 * cls_w[7] + cls_b[3];
    *(float4*)(out + (size_t)node * 4) = o;
    float* hout = out + (size_t)n * 4;
    *(float2*)(hout + (size_t)node * 2) = make_float2(p0, p1);
  }
}

extern "C" void kernel_launch(void* const* d_in, const int* in_sizes, int n_in,
                              void* d_out, int out_size, void* d_ws, size_t ws_size,
                              hipStream_t stream) {
  const float* x     = (const float*)d_in[0];
  const int*   ei    = (const int*)d_in[1];
  const float* fw    = (const float*)d_in[2];
  const float* fb    = (const float*)d_in[3];
  const float* w1    = (const float*)d_in[4];
  const float* b1    = (const float*)d_in[5];
  const float* w2    = (const float*)d_in[6];
  const float* b2    = (const float*)d_in[7];
  const float* cp_w  = (const float*)d_in[8];
  const float* cp_b  = (const float*)d_in[9];
  const float* cls_w = (const float*)d_in[10];
  const float* cls_b = (const float*)d_in[11];
  float* out = (float*)d_out;

  int n = in_sizes[0] / HDIM;
  int E = in_sizes[1] / 2;
  size_t nh = (size_t)n * HDIM;

  float* A = (float*)d_ws;                         // H0 -> h1 (fp32)
  __hip_bfloat16* Mb = (__hip_bfloat16*)(A + nh);  // messages (bf16)
  int* deg = (int*)((char*)Mb + nh * sizeof(__hip_bfloat16));
  int* off = deg + n;             // n+1 entries
  int* cur = off + n + 1;
  int* csr = cur + n;             // E entries
  int* partials = csr + E;        // up to 1024 entries

  int gemmBlocks = (n + BM - 1) / BM;
  int edgeBlocks = (E + 255) / 256;
  int aggBlocks = (n + 3) / 4;
  int G = (n + 1023) / 1024;      // scan chunks

  // CSR build (used by both layers)
  hipMemsetAsync(deg, 0, (size_t)n * sizeof(int), stream);
  hist_dst<<<edgeBlocks, 256, 0, stream>>>(ei, E, n, deg);
  scan1<<<G, 1024, 0, stream>>>(deg, partials, n);
  scan2<<<1, 1024, 0, stream>>>(partials, G);
  scan3<<<G, 1024, 0, stream>>>(deg, partials, off, cur, n);
  fill_csr<<<edgeBlocks, 256, 0, stream>>>(ei, E, n, cur, csr);

  // layer 0: A = x @ fw + fb (fp32)
  gemm_tiled<false><<<gemmBlocks, 256, 0, stream>>>(x, fw, fb, A, nullptr, n);
  // layer 1: Mb = bf16(A @ w1) ; A = tanh(b1 + agg(Mb))
  gemm_tiled<true><<<gemmBlocks, 256, 0, stream>>>(A, w1, nullptr, nullptr, Mb, n);
  agg_tanh<<<aggBlocks, 256, 0, stream>>>(Mb, off, csr, b1, A, n);
  // layer 2: Mb = bf16(A @ w2) ; fused agg + head
  gemm_tiled<true><<<gemmBlocks, 256, 0, stream>>>(A, w2, nullptr, nullptr, Mb, n);
  agg2_head<<<aggBlocks, 256, 0, stream>>>(Mb, off, csr, b2, cp_w, cp_b,
                                           cls_w, cls_b, out, n);
}

// Round 13
// 312.889 us; speedup vs baseline: 1.1300x; 1.1300x over previous
//
#include <hip/hip_runtime.h>
#include <hip/hip_bf16.h>

#define HDIM 128
#define BM 64
#define KB 16

// ---------------------------------------------------------------------------
// Tiled fp32 GEMM: out = A[n,128] @ W[128,128] (+bias), fp32 math.
// BF16OUT: epilogue converts to bf16 (messages consumed by the gather).
// ---------------------------------------------------------------------------
template <bool BF16OUT>
__global__ __launch_bounds__(256) void gemm_tiled(
    const float* __restrict__ A, const float* __restrict__ W,
    const float* __restrict__ bias, float* __restrict__ outf,
    __hip_bfloat16* __restrict__ outb, int n) {
  __shared__ float sA[KB][BM];    // transposed: sA[k][row]
  __shared__ float sW[KB][HDIM];
  const int tid = threadIdx.x;
  const int tx = tid & 15;        // col group: cols tx*8 .. tx*8+7
  const int ty = tid >> 4;        // row group: rows ty*4 .. ty*4+3
  const int block_row = blockIdx.x * BM;

  float acc[4][8];
#pragma unroll
  for (int i = 0; i < 4; ++i)
#pragma unroll
    for (int j = 0; j < 8; ++j) acc[i][j] = 0.f;

  const int ar = tid >> 2;        // 0..63: row this thread stages
  const int ak = (tid & 3) << 2;  // 0,4,8,12: k-offset staged
  const int wk = tid >> 4;        // 0..15: W k-row staged
  const int wc = (tid & 15) << 3; // col offset staged

  for (int k0 = 0; k0 < HDIM; k0 += KB) {
    float4 av = make_float4(0.f, 0.f, 0.f, 0.f);
    int grow = block_row + ar;
    if (grow < n) av = *(const float4*)(A + (size_t)grow * HDIM + k0 + ak);
    sA[ak + 0][ar] = av.x; sA[ak + 1][ar] = av.y;
    sA[ak + 2][ar] = av.z; sA[ak + 3][ar] = av.w;

    float4 w0 = *(const float4*)(W + (size_t)(k0 + wk) * HDIM + wc);
    float4 w1 = *(const float4*)(W + (size_t)(k0 + wk) * HDIM + wc + 4);
    *(float4*)&sW[wk][wc] = w0;
    *(float4*)&sW[wk][wc + 4] = w1;
    __syncthreads();

#pragma unroll
    for (int k = 0; k < KB; ++k) {
      float4 a = *(const float4*)&sA[k][ty * 4];
      float4 wA = *(const float4*)&sW[k][tx * 8];
      float4 wB = *(const float4*)&sW[k][tx * 8 + 4];
      float av4[4] = {a.x, a.y, a.z, a.w};
      float wv[8] = {wA.x, wA.y, wA.z, wA.w, wB.x, wB.y, wB.z, wB.w};
#pragma unroll
      for (int i = 0; i < 4; ++i)
#pragma unroll
        for (int j = 0; j < 8; ++j) acc[i][j] += av4[i] * wv[j];
    }
    __syncthreads();
  }

  float bj[8];
#pragma unroll
  for (int j = 0; j < 8; ++j) bj[j] = bias ? bias[tx * 8 + j] : 0.f;
#pragma unroll
  for (int i = 0; i < 4; ++i) {
    int grow = block_row + ty * 4 + i;
    if (grow < n) {
      float o[8];
#pragma unroll
      for (int j = 0; j < 8; ++j) o[j] = acc[i][j] + bj[j];
      if (BF16OUT) {
        uint32_t pk[4];
#pragma unroll
        for (int p = 0; p < 4; ++p) {
          uint32_t lo = __bfloat16_as_ushort(__float2bfloat16(o[2 * p]));
          uint32_t hi = __bfloat16_as_ushort(__float2bfloat16(o[2 * p + 1]));
          pk[p] = lo | (hi << 16);
        }
        *(uint4*)(outb + (size_t)grow * HDIM + tx * 8) = *(uint4*)pk;
      } else {
        *(float4*)(outf + (size_t)grow * HDIM + tx * 8) = *(float4*)&o[0];
        *(float4*)(outf + (size_t)grow * HDIM + tx * 8 + 4) = *(float4*)&o[4];
      }
    }
  }
}

// ---------------------------------------------------------------------------
// CSR build: histogram of dst, 3-kernel hierarchical exclusive scan, fill.
// ---------------------------------------------------------------------------
__global__ __launch_bounds__(256) void hist_dst(const int* __restrict__ ei,
                                                int E, int n,
                                                int* __restrict__ deg) {
  int e = blockIdx.x * 256 + threadIdx.x;
  if (e < E) {
    int s = ei[e];
    int d = ei[E + e];
    if ((unsigned)s < (unsigned)n && (unsigned)d < (unsigned)n)
      atomicAdd(&deg[d], 1);
  }
}

__global__ __launch_bounds__(1024) void scan1(const int* __restrict__ deg,
                                              int* __restrict__ partials, int n) {
  __shared__ int sm[1024];
  int i = blockIdx.x * 1024 + threadIdx.x;
  sm[threadIdx.x] = (i < n) ? deg[i] : 0;
  __syncthreads();
  for (int d = 512; d > 0; d >>= 1) {
    if (threadIdx.x < d) sm[threadIdx.x] += sm[threadIdx.x + d];
    __syncthreads();
  }
  if (threadIdx.x == 0) partials[blockIdx.x] = sm[0];
}

__global__ __launch_bounds__(1024) void scan2(int* __restrict__ partials, int G) {
  __shared__ int sm[1024];
  int tid = threadIdx.x;
  int v = (tid < G) ? partials[tid] : 0;
  sm[tid] = v;
  __syncthreads();
  for (int d = 1; d < 1024; d <<= 1) {
    int t = (tid >= d) ? sm[tid - d] : 0;
    __syncthreads();
    sm[tid] += t;
    __syncthreads();
  }
  if (tid < G) partials[tid] = sm[tid] - v;  // inclusive -> exclusive
}

__global__ __launch_bounds__(1024) void scan3(const int* __restrict__ deg,
                                              const int* __restrict__ partials,
                                              int* __restrict__ off,
                                              int* __restrict__ cur, int n) {
  __shared__ int sm[1024];
  int tid = threadIdx.x;
  int i = blockIdx.x * 1024 + tid;
  int v = (i < n) ? deg[i] : 0;
  sm[tid] = v;
  __syncthreads();
  for (int d = 1; d < 1024; d <<= 1) {
    int t = (tid >= d) ? sm[tid - d] : 0;
    __syncthreads();
    sm[tid] += t;
    __syncthreads();
  }
  if (i < n) {
    int ex = partials[blockIdx.x] + sm[tid] - v;
    off[i] = ex;
    cur[i] = ex;
    if (i == n - 1) off[n] = ex + v;
  }
}

__global__ __launch_bounds__(256) void fill_csr(const int* __restrict__ ei,
                                                int E, int n,
                                                int* __restrict__ cur,
                                                int* __restrict__ csr) {
  int e = blockIdx.x * 256 + threadIdx.x;
  if (e < E) {
    int s = ei[e];
    int d = ei[E + e];
    if ((unsigned)d < (unsigned)n && (unsigned)s < (unsigned)n) {
      int slot = atomicAdd(&cur[d], 1);
      csr[slot] = s;
    }
  }
}

// ---------------------------------------------------------------------------
// Gather core: fp32 accumulate of bf16 message rows.
// One wave per node (node is wave-uniform); lane owns feats 2*lane, 2*lane+1.
// node/off/csr values are pinned to SGPRs via readfirstlane: csr walk becomes
// scalar/broadcast loads, gather address = SGPR base + lane*4. 8-wide
// branch-free batches with NAMED registers keep 8 loads in flight (the R9
// array version was register-minimized to VGPR_Count=16 and serialized).
// ---------------------------------------------------------------------------
__device__ inline float2 bf2_unpack(uint32_t u) {
  float lo = __uint_as_float(u << 16);
  float hi = __uint_as_float(u & 0xffff0000u);
  return make_float2(lo, hi);
}

__device__ inline float2 gather_sum(const uint32_t* __restrict__ Mw,
                                    const int* __restrict__ off,
                                    const int* __restrict__ csr,
                                    int node, int lane) {
  // self loop
  float2 acc = bf2_unpack(Mw[(size_t)node * (HDIM / 2) + lane]);
  int s = __builtin_amdgcn_readfirstlane(off[node]);
  int e = __builtin_amdgcn_readfirstlane(off[node + 1]);
  int j = s;
  // 8-wide branch-free batches: all indices, then all loads, then unpack.
  for (; j + 8 <= e; j += 8) {
    int s0 = __builtin_amdgcn_readfirstlane(csr[j + 0]);
    int s1 = __builtin_amdgcn_readfirstlane(csr[j + 1]);
    int s2 = __builtin_amdgcn_readfirstlane(csr[j + 2]);
    int s3 = __builtin_amdgcn_readfirstlane(csr[j + 3]);
    int s4 = __builtin_amdgcn_readfirstlane(csr[j + 4]);
    int s5 = __builtin_amdgcn_readfirstlane(csr[j + 5]);
    int s6 = __builtin_amdgcn_readfirstlane(csr[j + 6]);
    int s7 = __builtin_amdgcn_readfirstlane(csr[j + 7]);
    uint32_t r0 = Mw[(size_t)s0 * (HDIM / 2) + lane];
    uint32_t r1 = Mw[(size_t)s1 * (HDIM / 2) + lane];
    uint32_t r2 = Mw[(size_t)s2 * (HDIM / 2) + lane];
    uint32_t r3 = Mw[(size_t)s3 * (HDIM / 2) + lane];
    uint32_t r4 = Mw[(size_t)s4 * (HDIM / 2) + lane];
    uint32_t r5 = Mw[(size_t)s5 * (HDIM / 2) + lane];
    uint32_t r6 = Mw[(size_t)s6 * (HDIM / 2) + lane];
    uint32_t r7 = Mw[(size_t)s7 * (HDIM / 2) + lane];
    float2 v0 = bf2_unpack(r0), v1 = bf2_unpack(r1);
    float2 v2 = bf2_unpack(r2), v3 = bf2_unpack(r3);
    float2 v4 = bf2_unpack(r4), v5 = bf2_unpack(r5);
    float2 v6 = bf2_unpack(r6), v7 = bf2_unpack(r7);
    acc.x += v0.x; acc.y += v0.y;
    acc.x += v1.x; acc.y += v1.y;
    acc.x += v2.x; acc.y += v2.y;
    acc.x += v3.x; acc.y += v3.y;
    acc.x += v4.x; acc.y += v4.y;
    acc.x += v5.x; acc.y += v5.y;
    acc.x += v6.x; acc.y += v6.y;
    acc.x += v7.x; acc.y += v7.y;
  }
  // 4-wide batch
  for (; j + 4 <= e; j += 4) {
    int s0 = __builtin_amdgcn_readfirstlane(csr[j + 0]);
    int s1 = __builtin_amdgcn_readfirstlane(csr[j + 1]);
    int s2 = __builtin_amdgcn_readfirstlane(csr[j + 2]);
    int s3 = __builtin_amdgcn_readfirstlane(csr[j + 3]);
    uint32_t r0 = Mw[(size_t)s0 * (HDIM / 2) + lane];
    uint32_t r1 = Mw[(size_t)s1 * (HDIM / 2) + lane];
    uint32_t r2 = Mw[(size_t)s2 * (HDIM / 2) + lane];
    uint32_t r3 = Mw[(size_t)s3 * (HDIM / 2) + lane];
    float2 v0 = bf2_unpack(r0), v1 = bf2_unpack(r1);
    float2 v2 = bf2_unpack(r2), v3 = bf2_unpack(r3);
    acc.x += v0.x; acc.y += v0.y;
    acc.x += v1.x; acc.y += v1.y;
    acc.x += v2.x; acc.y += v2.y;
    acc.x += v3.x; acc.y += v3.y;
  }
  // scalar tail
  for (; j < e; ++j) {
    int s0 = __builtin_amdgcn_readfirstlane(csr[j]);
    float2 v0 = bf2_unpack(Mw[(size_t)s0 * (HDIM / 2) + lane]);
    acc.x += v0.x; acc.y += v0.y;
  }
  return acc;
}

// agg_tanh: out[v] = tanh(bias + self + neighbor sum), fp32 out.
__global__ __launch_bounds__(256) void agg_tanh(
    const __hip_bfloat16* __restrict__ M, const int* __restrict__ off,
    const int* __restrict__ csr, const float* __restrict__ bias,
    float* __restrict__ out, int n) {
  int node = (blockIdx.x * 256 + threadIdx.x) >> 6;
  int lane = threadIdx.x & 63;
  if (node >= n) return;
  int f = lane * 2;
  float2 acc = gather_sum((const uint32_t*)M, off, csr, node, lane);
  acc.x = tanhf(acc.x + bias[f]);
  acc.y = tanhf(acc.y + bias[f + 1]);
  *(float2*)(out + (size_t)node * HDIM + f) = acc;
}

// agg2_head: layer-2 aggregation fused with class_prepare + classifier.
// d_out = [n*4 logits][n*2 hp].
__global__ __launch_bounds__(256) void agg2_head(
    const __hip_bfloat16* __restrict__ M, const int* __restrict__ off,
    const int* __restrict__ csr, const float* __restrict__ b2,
    const float* __restrict__ cp_w, const float* __restrict__ cp_b,
    const float* __restrict__ cls_w, const float* __restrict__ cls_b,
    float* __restrict__ out, int n) {
  int node = (blockIdx.x * 256 + threadIdx.x) >> 6;
  int lane = threadIdx.x & 63;
  if (node >= n) return;
  int f = lane * 2;
  float2 acc = gather_sum((const uint32_t*)M, off, csr, node, lane);
  float h0 = tanhf(acc.x + b2[f]);
  float h1 = tanhf(acc.y + b2[f + 1]);
  float4 w = *(const float4*)(cp_w + lane * 4);  // rows f, f+1 of [128,2]
  float s0 = h0 * w.x + h1 * w.z;
  float s1 = h0 * w.y + h1 * w.w;
#pragma unroll
  for (int offs = 32; offs; offs >>= 1) {
    s0 += __shfl_xor(s0, offs);
    s1 += __shfl_xor(s1, offs);
  }
  if (lane == 0) {
    float p0 = tanhf(s0 + cp_b[0]);
    float p1 = tanhf(s1 + cp_b[1]);
    float4 o;
    o.x = p0 * cls_w[0] + p1 * cls_w[4] + cls_b[0];
    o.y = p0 * cls_w[1] + p1 * cls_w[5] + cls_b[1];
    o.z = p0 * cls_w[2] + p1 * cls_w[6] + cls_b[2];
    o.w = p0 * cls_w[3] + p1 * cls_w[7] + cls_b[3];
    *(float4*)(out + (size_t)node * 4) = o;
    float* hout = out + (size_t)n * 4;
    *(float2*)(hout + (size_t)node * 2) = make_float2(p0, p1);
  }
}

extern "C" void kernel_launch(void* const* d_in, const int* in_sizes, int n_in,
                              void* d_out, int out_size, void* d_ws, size_t ws_size,
                              hipStream_t stream) {
  const float* x     = (const float*)d_in[0];
  const int*   ei    = (const int*)d_in[1];
  const float* fw    = (const float*)d_in[2];
  const float* fb    = (const float*)d_in[3];
  const float* w1    = (const float*)d_in[4];
  const float* b1    = (const float*)d_in[5];
  const float* w2    = (const float*)d_in[6];
  const float* b2    = (const float*)d_in[7];
  const float* cp_w  = (const float*)d_in[8];
  const float* cp_b  = (const float*)d_in[9];
  const float* cls_w = (const float*)d_in[10];
  const float* cls_b = (const float*)d_in[11];
  float* out = (float*)d_out;

  int n = in_sizes[0] / HDIM;
  int E = in_sizes[1] / 2;
  size_t nh = (size_t)n * HDIM;

  float* A = (float*)d_ws;                         // H0 -> h1 (fp32)
  __hip_bfloat16* Mb = (__hip_bfloat16*)(A + nh);  // messages (bf16)
  int* deg = (int*)((char*)Mb + nh * sizeof(__hip_bfloat16));
  int* off = deg + n;             // n+1 entries
  int* cur = off + n + 1;
  int* csr = cur + n;             // E entries
  int* partials = csr + E;        // up to 1024 entries

  int gemmBlocks = (n + BM - 1) / BM;
  int edgeBlocks = (E + 255) / 256;
  int aggBlocks = (n + 3) / 4;
  int G = (n + 1023) / 1024;      // scan chunks

  // CSR build (used by both layers)
  hipMemsetAsync(deg, 0, (size_t)n * sizeof(int), stream);
  hist_dst<<<edgeBlocks, 256, 0, stream>>>(ei, E, n, deg);
  scan1<<<G, 1024, 0, stream>>>(deg, partials, n);
  scan2<<<1, 1024, 0, stream>>>(partials, G);
  scan3<<<G, 1024, 0, stream>>>(deg, partials, off, cur, n);
  fill_csr<<<edgeBlocks, 256, 0, stream>>>(ei, E, n, cur, csr);

  // layer 0: A = x @ fw + fb (fp32)
  gemm_tiled<false><<<gemmBlocks, 256, 0, stream>>>(x, fw, fb, A, nullptr, n);
  // layer 1: Mb = bf16(A @ w1) ; A = tanh(b1 + agg(Mb))
  gemm_tiled<true><<<gemmBlocks, 256, 0, stream>>>(A, w1, nullptr, nullptr, Mb, n);
  agg_tanh<<<aggBlocks, 256, 0, stream>>>(Mb, off, csr, b1, A, n);
  // layer 2: Mb = bf16(A @ w2) ; fused agg + head
  gemm_tiled<true><<<gemmBlocks, 256, 0, stream>>>(A, w2, nullptr, nullptr, Mb, n);
  agg2_head<<<aggBlocks, 256, 0, stream>>>(Mb, off, csr, b2, cp_w, cp_b,
                                           cls_w, cls_b, out, n);
}